// Round 17
// baseline (79.291 us; speedup 1.0000x reference)
//
#include <hip/hip_runtime.h>
#include <hip/hip_bf16.h>
#include <cstdint>

#define B_ 8
#define C_ 128
#define N_ 16384   // H*W
#define CHN 512    // n per KA block
#define SN 128     // n per subtile
#define NST 4      // subtiles per KA block
#define NC (N_ / CHN)  // 32 chunks

typedef __attribute__((ext_vector_type(8))) short short8;
typedef __attribute__((ext_vector_type(4))) float f32x4;
typedef __attribute__((ext_vector_type(4))) unsigned short us4;
typedef unsigned short u16;

__device__ __forceinline__ short f2bf(float f) {
  union { float f; unsigned u; } c; c.f = f;
  unsigned r = (c.u + 0x7FFFu + ((c.u >> 16) & 1u)) >> 16;
  return (short)r;
}

__device__ __forceinline__ unsigned cvtpk(float lo, float hi) {
  unsigned r;
  asm("v_cvt_pk_bf16_f32 %0, %1, %2" : "=v"(r) : "v"(lo), "v"(hi));
  return r;
}

union SB { short8 s8; unsigned u[4]; };

// ---------------------------------------------------------------------------
// K0: preconvert k_w, v_w (fp32) -> wbf (bf16 [2][128][128])
// ---------------------------------------------------------------------------
__global__ __launch_bounds__(256) void k0_wcvt(const float* __restrict__ kw,
                                               const float* __restrict__ vw,
                                               u16* __restrict__ wbf) {
  const int g = blockIdx.x * 256 + threadIdx.x;  // 0..8191 float4s
  const int mat = g >> 12, o4 = g & 4095;
  const float* src = mat ? vw : kw;
  float4 f = reinterpret_cast<const float4*>(src)[o4];
  us4 s;
  s[0] = (u16)f2bf(f.x); s[1] = (u16)f2bf(f.y);
  s[2] = (u16)f2bf(f.z); s[3] = (u16)f2bf(f.w);
  reinterpret_cast<us4*>(wbf + (size_t)mat * C_ * C_)[o4] = s;
}

// ---------------------------------------------------------------------------
// Staging (vectorized, r15 form).  KA variant uses NON-TEMPORAL loads:
// kv is read exactly once — nt keeps it from evicting q/part in L3.
// ---------------------------------------------------------------------------
#define STAGE_LOADS_NT(BASE_, ST_) do {                                      \
  _Pragma("unroll") for (int i_ = 0; i_ < 8; ++i_)                           \
    xf[i_] = __builtin_nontemporal_load(reinterpret_cast<const f32x4*>(      \
        (BASE_) + (size_t)((lane >> 5) * 8 + i_) * N_ + (ST_) * SN +         \
        (lane & 31) * 4));                                                   \
} while (0)

#define STAGE_XWRITE(BUF_) do {                                              \
  const int db_ = w * 16 + (lane >> 5) * 8;                                  \
  _Pragma("unroll") for (int k_ = 0; k_ < 4; ++k_) {                         \
    const int n_ = (lane & 31) * 4 + k_;                                     \
    uint4 q_;                                                                \
    q_.x = cvtpk(xf[0][k_], xf[1][k_]);                                      \
    q_.y = cvtpk(xf[2][k_], xf[3][k_]);                                      \
    q_.z = cvtpk(xf[4][k_], xf[5][k_]);                                      \
    q_.w = cvtpk(xf[6][k_], xf[7][k_]);                                      \
    *reinterpret_cast<uint4*>(                                               \
        (BUF_) + n_ * SN + (db_ ^ ((n_ & 7) << 3))) = q_;                    \
  }                                                                          \
} while (0)

// ---------------------------------------------------------------------------
// KA: fused projection + context partial (rounds 6-16 core, passed 0.03125)
// with chunked XCD remap; staging loads vectorized + non-temporal.
// ---------------------------------------------------------------------------
__global__ __launch_bounds__(512, 2) void ka_projctx(
    const float* __restrict__ kv, const u16* __restrict__ wbf,
    const float* __restrict__ kb, const float* __restrict__ vb,
    float* __restrict__ part, float* __restrict__ zpart) {
  __shared__ u16 xt[2][C_ * SN];   // 2 x 32 KB transposed bf16 x
  __shared__ u16 eks[C_ * SN];     // 32 KB EK stash [d][n]
  __shared__ u16 vs [C_ * SN];     // 32 KB V  stash [c][n]

  const int fid = blockIdx.x + blockIdx.y * NC;
  const int fid2 = (fid & 7) * 32 + (fid >> 3);  // XCD k -> batch k
  const int b = fid2 >> 5, kc = fid2 & 31;
  const int tid = threadIdx.x;
  const int w = tid >> 6, lane = tid & 63;
  const int lg = lane >> 4, li = lane & 15;
  const int mat = w >> 2, dblk = w & 3;
  const int cg = w >> 1, dh = w & 1;

  const float* xb = kv + (size_t)b * C_ * N_ + (size_t)kc * CHN;
  const float* xw = xb + (size_t)(w * 16) * N_;  // wave's 16 c-rows
  const u16* Wm = wbf + (size_t)mat * C_ * C_;
  const float* biasp = mat ? vb : kb;
  u16* S = mat ? vs : eks;

  short8 wreg[2][4];
#pragma unroll
  for (int dt = 0; dt < 2; ++dt)
#pragma unroll
    for (int ks = 0; ks < 4; ++ks)
      wreg[dt][ks] = *reinterpret_cast<const short8*>(
          Wm + (dblk * 32 + dt * 16 + li) * C_ + ks * 32 + lg * 8);
  float bias2[2];
#pragma unroll
  for (int dt = 0; dt < 2; ++dt) bias2[dt] = biasp[dblk * 32 + dt * 16 + li];

  f32x4 acc[2][4] = {};   // ctx accumulator [am c][dt d]
  float zac[2] = {0.f, 0.f};
  f32x4 xf[8];            // reg-staged x: 8 d-rows x 4 n

  STAGE_LOADS_NT(xw, 0);
  STAGE_XWRITE(&xt[0][0]);
  STAGE_LOADS_NT(xw, 1);
  asm volatile("s_waitcnt lgkmcnt(0)" ::: "memory");
  __builtin_amdgcn_s_barrier();
  __builtin_amdgcn_sched_barrier(0);

#pragma unroll
  for (int st = 0; st < NST; ++st) {
    const u16* xc = &xt[st & 1][0];

    if (st < NST - 1) {
      STAGE_XWRITE(&xt[(st + 1) & 1][0]);
      if (st < NST - 2) STAGE_LOADS_NT(xw, st + 2);
    }

    // ---- proj: D[n][d] = xT · W^T, in nt-pairs ----
#pragma unroll
    for (int h2 = 0; h2 < 4; ++h2) {
      f32x4 pacc[2][2] = {};  // [ntl][dt]
#pragma unroll
      for (int ntl = 0; ntl < 2; ++ntl) {
        const int n = (h2 * 2 + ntl) * 16 + li;
#pragma unroll
        for (int ks = 0; ks < 4; ++ks) {
          short8 a = *reinterpret_cast<const short8*>(
              xc + n * SN + ((ks * 32 + lg * 8) ^ ((n & 7) << 3)));
#pragma unroll
          for (int dt = 0; dt < 2; ++dt)
            pacc[ntl][dt] = __builtin_amdgcn_mfma_f32_16x16x32_bf16(
                a, wreg[dt][ks], pacc[ntl][dt], 0, 0, 0);
        }
      }
#pragma unroll
      for (int dt = 0; dt < 2; ++dt) {
        const int d = dblk * 32 + dt * 16 + li;
        const float bias = bias2[dt];
#pragma unroll
        for (int ntl = 0; ntl < 2; ++ntl) {
          float v0 = pacc[ntl][dt][0] + bias;
          float v1 = pacc[ntl][dt][1] + bias;
          float v2 = pacc[ntl][dt][2] + bias;
          float v3 = pacc[ntl][dt][3] + bias;
          if (mat == 0) {
            v0 = __expf(v0); v1 = __expf(v1); v2 = __expf(v2); v3 = __expf(v3);
            zac[dt] += (v0 + v1) + (v2 + v3);
          }
          const int nq = (h2 * 2 + ntl) * 16 + lg * 4;
          uint2 pk; pk.x = cvtpk(v0, v1); pk.y = cvtpk(v2, v3);
          *reinterpret_cast<uint2*>(S + d * SN + (nq ^ ((d & 7) << 3))) = pk;
        }
      }
    }
    asm volatile("s_waitcnt lgkmcnt(0)" ::: "memory");
    __builtin_amdgcn_s_barrier();
    __builtin_amdgcn_sched_barrier(0);

    // ---- ctx: part += V·EK^T over this subtile's 128 n ----
#pragma unroll
    for (int kk = 0; kk < 4; ++kk) {
      const int n0 = kk * 32 + lg * 8;
      short8 a[2], bb[4];
#pragma unroll
      for (int am = 0; am < 2; ++am) {
        const int c = cg * 32 + am * 16 + li;
        a[am] = *reinterpret_cast<const short8*>(vs + c * SN + (n0 ^ ((c & 7) << 3)));
      }
#pragma unroll
      for (int dt = 0; dt < 4; ++dt) {
        const int d = dh * 64 + dt * 16 + li;
        bb[dt] = *reinterpret_cast<const short8*>(eks + d * SN + (n0 ^ ((d & 7) << 3)));
      }
#pragma unroll
      for (int am = 0; am < 2; ++am)
#pragma unroll
        for (int dt = 0; dt < 4; ++dt)
          acc[am][dt] = __builtin_amdgcn_mfma_f32_16x16x32_bf16(a[am], bb[dt], acc[am][dt], 0, 0, 0);
    }
    asm volatile("s_waitcnt lgkmcnt(0)" ::: "memory");
    __builtin_amdgcn_s_barrier();
    __builtin_amdgcn_sched_barrier(0);
  }

  // ---- epilogue: part + zpart (deterministic, no atomics) ----
  float* P = part + ((size_t)kc * B_ + b) * C_ * C_;
#pragma unroll
  for (int am = 0; am < 2; ++am)
#pragma unroll
    for (int dt = 0; dt < 4; ++dt)
#pragma unroll
      for (int r = 0; r < 4; ++r) {
        const int c = cg * 32 + am * 16 + lg * 4 + r;
        const int d = dh * 64 + dt * 16 + li;
        P[c * C_ + d] = acc[am][dt][r];
      }
  if (mat == 0) {
#pragma unroll
    for (int dt = 0; dt < 2; ++dt) {
      float z = zac[dt];
      z += __shfl_xor(z, 16);
      z += __shfl_xor(z, 32);
      if (lg == 0)
        zpart[((size_t)kc * B_ + b) * C_ + dblk * 32 + dt * 16 + li] = z;
    }
  }
}

// ---------------------------------------------------------------------------
// KB2: cs = (sum_kc part)/Z ; M = cs·qw (bf16), T = cs·qb
// (unchanged from rounds 8-16)
// ---------------------------------------------------------------------------
__global__ __launch_bounds__(256) void kb2_fin(
    const float* __restrict__ part, const float* __restrict__ zpart,
    const float* __restrict__ qw, const float* __restrict__ qb,
    u16* __restrict__ M, float* __restrict__ T) {
  const int b = blockIdx.y;
  const int cs0 = blockIdx.x * 16;
  const int tid = threadIdx.x;
  __shared__ float cs[16][128];
  __shared__ float Zs[128];
  if (tid < 128) {
    float s = 0.f;
    for (int kc = 0; kc < NC; ++kc)
      s += zpart[((size_t)kc * B_ + b) * C_ + tid];
    Zs[tid] = s;
  }
  __syncthreads();
#pragma unroll
  for (int i = 0; i < 8; ++i) {
    const int e = tid + i * 256;
    const int cl = e >> 7, d = e & 127;
    float s = 0.f;
    for (int kc = 0; kc < NC; ++kc)
      s += part[(((size_t)kc * B_ + b) * C_ + (cs0 + cl)) * C_ + d];
    cs[cl][d] = s / Zs[d];
  }
  __syncthreads();
  const int cl = tid >> 4, e0 = (tid & 15) * 8;
  float m[8] = {};
  for (int d = 0; d < 128; ++d) {
    const float cv = cs[cl][d];
    const float* qr = qw + d * C_ + e0;
#pragma unroll
    for (int j = 0; j < 8; ++j) m[j] += cv * qr[j];
  }
  u16* mp = M + ((size_t)b * C_ + cs0 + cl) * C_ + e0;
#pragma unroll
  for (int j = 0; j < 8; ++j) mp[j] = (u16)f2bf(m[j]);
  if (tid < 16) {
    float tv = 0.f;
    for (int d = 0; d < 128; ++d) tv += cs[tid][d] * qb[d];
    T[b * C_ + cs0 + tid] = tv;
  }
}

// ---------------------------------------------------------------------------
// K4 v9: round-16 structure (one 128x128 subtile per block, grid (128,B),
// 256 thr, reg-held acc, single deferred write burst) with the out stores
// NON-TEMPORAL: out is write-once, nt keeps its 64 MB of dirty lines from
// churning L3 so q stays L3-resident across replays.  q loads stay normal
// (cached) on purpose.  Store values bit-identical to r16.
// ---------------------------------------------------------------------------
#define K4_LOADS(H_) do {                                                    \
  _Pragma("unroll") for (int i_ = 0; i_ < 8; ++i_)                           \
    xf[i_] = *reinterpret_cast<const f32x4*>(                                \
        qsrc + (size_t)((H_) * 16 + (lane >> 5) * 8 + i_) * N_ +             \
        (lane & 31) * 4);                                                    \
} while (0)

#define K4_XWRITE(H_) do {                                                   \
  const int db_ = w * 32 + (H_) * 16 + (lane >> 5) * 8;                      \
  _Pragma("unroll") for (int k_ = 0; k_ < 4; ++k_) {                         \
    const int n_ = (lane & 31) * 4 + k_;                                     \
    uint4 q_;                                                                \
    q_.x = cvtpk(xf[0][k_], xf[1][k_]);                                      \
    q_.y = cvtpk(xf[2][k_], xf[3][k_]);                                      \
    q_.z = cvtpk(xf[4][k_], xf[5][k_]);                                      \
    q_.w = cvtpk(xf[6][k_], xf[7][k_]);                                      \
    *reinterpret_cast<uint4*>(                                               \
        qt + n_ * SN + (db_ ^ ((n_ & 7) << 3))) = q_;                        \
  }                                                                          \
} while (0)

__global__ __launch_bounds__(256) void k4_out(const u16* __restrict__ M,
                                              const float* __restrict__ T,
                                              const float* __restrict__ q,
                                              float* __restrict__ out) {
  __shared__ u16 qt[SN * C_];  // [n][d] bf16 swizzled, 32 KB

  const int fid = blockIdx.x + blockIdx.y * 128;   // [0,1024)
  const int fid2 = (fid & 7) * 128 + (fid >> 3);   // XCD k -> batch k
  const int b = fid2 >> 7, nc = fid2 & 127;
  const int nb = nc * SN;
  const int tid = threadIdx.x;
  const int w = tid >> 6, lane = tid & 63;
  const int lg = lane >> 4, li = lane & 15;

  // staging source: wave w owns d-rows [w*32, +32), two 16-row halves
  const float* qsrc = q + (size_t)b * C_ * N_ + nb + (size_t)(w * 32) * N_;

  // M fragments (A operand rows c = w*32+ct*16+li) + T (per output row)
  short8 mreg[2][4];
  const u16* Mb = M + (size_t)b * C_ * C_;
#pragma unroll
  for (int ct = 0; ct < 2; ++ct)
#pragma unroll
    for (int ks = 0; ks < 4; ++ks)
      mreg[ct][ks] = *reinterpret_cast<const short8*>(
          Mb + (w * 32 + ct * 16 + li) * C_ + ks * 32 + lg * 8);
  float tcv[2][4];
#pragma unroll
  for (int ct = 0; ct < 2; ++ct)
#pragma unroll
    for (int r = 0; r < 4; ++r)
      tcv[ct][r] = T[b * C_ + w * 32 + ct * 16 + lg * 4 + r];

  // ---- stage: 128x128 fp32 -> bf16 qt, two half-stages ----
  f32x4 xf[8];
  K4_LOADS(0);
  K4_XWRITE(0);
  K4_LOADS(1);
  K4_XWRITE(1);
  __syncthreads();

  // ---- MFMA: D[c][n]; wave w owns c in [w*32,+32), n in [0,128) ----
  f32x4 acc[2][8] = {};  // [ct][nt]
#pragma unroll
  for (int nt = 0; nt < 8; ++nt) {
    const int n = nt * 16 + li;
#pragma unroll
    for (int ks = 0; ks < 4; ++ks) {
      short8 bb = *reinterpret_cast<const short8*>(
          qt + n * SN + ((ks * 32 + lg * 8) ^ ((n & 7) << 3)));
#pragma unroll
      for (int ct = 0; ct < 2; ++ct)
        acc[ct][nt] = __builtin_amdgcn_mfma_f32_16x16x32_bf16(
            mreg[ct][ks], bb, acc[ct][nt], 0, 0, 0);
    }
  }

  // ---- epilogue: single deferred NON-TEMPORAL write burst (64 KB) ----
#pragma unroll
  for (int ct = 0; ct < 2; ++ct)
#pragma unroll
    for (int r = 0; r < 4; ++r) {
      const int c = w * 32 + ct * 16 + lg * 4 + r;
      float* op = out + ((size_t)b * C_ + c) * N_ + nb;
      const float t = tcv[ct][r];
#pragma unroll
      for (int nt = 0; nt < 8; ++nt)
        __builtin_nontemporal_store(acc[ct][nt][r] + t, op + nt * 16 + li);
    }
}

// ---------------------------------------------------------------------------
extern "C" void kernel_launch(void* const* d_in, const int* in_sizes, int n_in,
                              void* d_out, int out_size, void* d_ws, size_t ws_size,
                              hipStream_t stream) {
  const float* q_feat  = (const float*)d_in[0];
  const float* kv_feat = (const float*)d_in[1];
  const float* q_w = (const float*)d_in[2];
  const float* q_b = (const float*)d_in[3];
  const float* k_w = (const float*)d_in[4];
  const float* k_b = (const float*)d_in[5];
  const float* v_w = (const float*)d_in[6];
  const float* v_b = (const float*)d_in[7];
  float* out = (float*)d_out;

  char* ws = (char*)d_ws;
  const size_t szPart = (size_t)NC * B_ * C_ * C_ * sizeof(float);  // 16 MB
  const size_t szZp   = (size_t)NC * B_ * C_ * sizeof(float);       // 128 KB
  const size_t szWbf  = (size_t)2 * C_ * C_ * sizeof(u16);          // 64 KB
  const size_t szM    = (size_t)B_ * C_ * C_ * sizeof(u16);         // 256 KB

  float* part  = (float*)ws;
  float* zpart = (float*)(ws + szPart);
  u16*   wbf   = (u16*)(ws + szPart + szZp);
  u16*   M     = (u16*)(ws + szPart + szZp + szWbf);
  float* T     = (float*)(ws + szPart + szZp + szWbf + szM);

  k0_wcvt<<<dim3(32), 256, 0, stream>>>(k_w, v_w, wbf);
  ka_projctx<<<dim3(NC, B_), 512, 0, stream>>>(kv_feat, wbf, k_b, v_b, part, zpart);
  kb2_fin<<<dim3(8, B_), 256, 0, stream>>>(part, zpart, q_w, q_b, M, T);
  k4_out<<<dim3(128, B_), 256, 0, stream>>>(M, T, q_feat, out);
}